// Round 7
// baseline (57.524 us; speedup 1.0000x reference)
//
#include <hip/hip_runtime.h>

// EqFrePBC: frequency-domain perturbation compensation, single kernel + MALL-coherent flags.
// B=2, L=2048, N=2 modes, pairs = full 40x40 grid (n1,n2 in [-20,19]).
//   G[b,m,d]    = sum_n xf[b,m,n]*conj(xf[b,(m-(d-20))%L,n])
//   S2[b,d,l]   = sum_{n1i} w[n1i,d] * G[b,(l-(n1i-20))%L,d]
//   dfreq[b,n,l]= sum_d S2[b,d,l] * xf[b,n,(l-(d-20))%L]
// Bias is constant over freq -> IFFT puts it only at t=0, cropped out.
// Structure (measured): 3-kernel graph floor ~23us (launch overhead); cg grid.sync ~15us/sync;
// threadfence-everywhere barrier ~14us/sync (L2 wb+inv per block). This version: cross-phase
// data via sc1 (agent-scope atomic) accesses that bypass the non-coherent per-XCD L2, so the
// phase flags need no cache flush: ready-flag (4 FFT producers) and done-flag (80 P2 blocks,
// one threadfence each to push fp32 atomics to the coherence point).
// Node 0: hipMemsetAsync zeroes df + flags. Node 1: fused kernel, 80 blk x 512.

#define L_FFT 2048
#define NB 2
#define NM 2
#define ND 40
#define CROP 20
#define LOUT 2008
#define NBLK 80
#define NT 512
#define SLAB 591   // 512 + 79
#define GSZ 551    // 512 + 39

__device__ __forceinline__ float2 cmul(float2 a, float2 b) {
    return make_float2(a.x*b.x - a.y*b.y, a.x*b.y + a.y*b.x);
}
__device__ __forceinline__ float2 cmulc(float2 a, float2 b) {  // a * conj(b)
    return make_float2(a.x*b.x + a.y*b.y, a.y*b.x - a.x*b.y);
}

// sc1 (agent-scope) 8-byte store/load: bypass per-XCD L2, coherent at MALL.
__device__ __forceinline__ void agent_store(float2* p, float2 v) {
    __hip_atomic_store((unsigned long long*)p,
                       __builtin_bit_cast(unsigned long long, v),
                       __ATOMIC_RELAXED, __HIP_MEMORY_SCOPE_AGENT);
}
__device__ __forceinline__ float2 agent_load(const float2* p) {
    unsigned long long u =
        __hip_atomic_load((const unsigned long long*)p,
                          __ATOMIC_RELAXED, __HIP_MEMORY_SCOPE_AGENT);
    return __builtin_bit_cast(float2, u);
}

// tw[t] = exp(SIGN * i * 2*pi*t/2048), t in [0,512)
template<int SIGN>
__device__ void build_tw(float2* tw, int tid) {
    if (tid < 512) {
        float ang = (float)(SIGN * tid) * 3.0679615757712823e-03f;  // 2*pi/2048
        tw[tid] = make_float2(__cosf(ang), __sinf(ang));
    }
}

// Radix-4 Stockham FFT, 2048 pts, 512 threads (5 radix-4 stages + 1 radix-2).
template<int SIGN>
__device__ float2* fft2048_r4(float2* bufA, float2* bufB, const float2* tw, int tid) {
    float2* src = bufA;
    float2* dst = bufB;
    #pragma unroll
    for (int m = 1; m <= 256; m *= 4) {
        __syncthreads();
        int k2 = tid & (m - 1);
        int jm = tid - k2;                     // m*j2, < 512
        float2 A = src[tid];
        float2 C = src[tid + 512];
        float2 B = src[tid + 1024];
        float2 D = src[tid + 1536];
        float2 T0 = make_float2(A.x + B.x, A.y + B.y);
        float2 T1 = make_float2(A.x - B.x, A.y - B.y);
        float2 T2 = make_float2(C.x + D.x, C.y + D.y);
        float2 cd = make_float2(C.x - D.x, C.y - D.y);
        float2 T3 = (SIGN < 0) ? make_float2(cd.y, -cd.x)    // -i*(C-D)
                               : make_float2(-cd.y, cd.x);   // +i*(C-D)
        float2 w1 = tw[jm];
        float2 w2 = cmul(w1, w1);
        float2 w3 = cmul(w2, w1);
        int base = 4 * jm + k2;
        dst[base]         = make_float2(T0.x + T2.x, T0.y + T2.y);
        dst[base + m]     = cmul(make_float2(T1.x + T3.x, T1.y + T3.y), w1);
        dst[base + 2*m]   = cmul(make_float2(T0.x - T2.x, T0.y - T2.y), w2);
        dst[base + 3*m]   = cmul(make_float2(T1.x - T3.x, T1.y - T3.y), w3);
        float2* t = src; src = dst; dst = t;
    }
    __syncthreads();
    // final radix-2 stage, m=1024: twiddle w^0 = 1
    #pragma unroll
    for (int it = 0; it < 2; ++it) {
        int q = tid + it * 512;
        float2 a = src[q];
        float2 b = src[q + 1024];
        dst[q]        = make_float2(a.x + b.x, a.y + b.y);
        dst[q + 1024] = make_float2(a.x - b.x, a.y - b.y);
    }
    float2* res = dst;
    __syncthreads();
    return res;
}

__global__ __launch_bounds__(NT) void fused_kernel(const float* __restrict__ xr,
                                                   const float* __restrict__ xi,
                                                   const float* __restrict__ task,
                                                   const float* __restrict__ wr,
                                                   const float* __restrict__ wi,
                                                   float* __restrict__ out,
                                                   float2* __restrict__ xf,
                                                   float* __restrict__ df,
                                                   int* __restrict__ cnt) {
    __shared__ float2 sm[4608];        // 36 KB, re-purposed per phase
    __shared__ float wrs[ND][4], wis[ND][4];
    int blk = blockIdx.x;
    int tid = threadIdx.x;
    float2* bufA = sm;
    float2* bufB = sm + 2048;
    float2* tw   = sm + 4096;

    // ---------------- P1: forward FFT for (b,n) = blk, blocks 0-3 ----------------
    if (blk < NB * NM) {
        int b = blk >> 1, n = blk & 1;
        #pragma unroll
        for (int it = 0; it < 4; ++it) {
            int t = tid + it * NT;
            int gi = (b * L_FFT + t) * NM + n;
            bufA[t] = make_float2(xr[gi], xi[gi]);
        }
        build_tw<-1>(tw, tid);
        float2* res = fft2048_r4<-1>(bufA, bufB, tw, tid);
        #pragma unroll
        for (int it = 0; it < 4; ++it) {
            int f = tid + it * NT;
            agent_store(&xf[blk * L_FFT + f], res[f]);   // sc1: lands at MALL
        }
        __syncthreads();   // barrier lowering drains each wave's vmcnt -> stores performed
        if (tid == 0)
            __hip_atomic_fetch_add(&cnt[0], 1, __ATOMIC_RELAXED, __HIP_MEMORY_SCOPE_AGENT);
    }
    // wait for all 4 xf slices
    if (tid == 0)
        while (__hip_atomic_load(&cnt[0], __ATOMIC_RELAXED, __HIP_MEMORY_SCOPE_AGENT) < NB * NM)
            __builtin_amdgcn_s_sleep(1);
    __syncthreads();

    // ---------------- P2: G + S2 + deltaf-scatter, (b, d-quad, l-tile of 512) ----
    {
        int b   = blk / 40;
        int rem = blk % 40;
        int dq  = rem >> 2;          // d-quad, 0..9
        int l0  = (rem & 3) << 9;    // l-tile origin
        float2* xs0 = sm;
        float2* xs1 = sm + SLAB;
        float2* Gs  = sm + 2 * SLAB;
        const float2* x0 = xf + (b * 2 + 0) * L_FFT;
        const float2* x1 = xf + (b * 2 + 1) * L_FFT;
        for (int i = tid; i < SLAB; i += NT) {
            int m = (l0 - 39 + i) & (L_FFT - 1);
            xs0[i] = agent_load(&x0[m]);                 // sc1: read from MALL
            xs1[i] = agent_load(&x1[m]);
        }
        if (tid < 160) {
            int n1i = tid >> 2, di = tid & 3;
            wrs[n1i][di] = wr[n1i * ND + dq * 4 + di];
            wis[n1i][di] = wi[n1i * ND + dq * 4 + di];
        }
        __syncthreads();
        float2 a0 = make_float2(0.f, 0.f);   // df accum, mode 0
        float2 a1 = make_float2(0.f, 0.f);   // df accum, mode 1
        #pragma unroll
        for (int di = 0; di < 4; ++di) {
            int d  = dq * 4 + di;
            int dd = d - 20;
            // Gs[j] = G[b, l0-19+j, d], j in [0, GSZ)
            for (int j = tid; j < GSZ; j += NT) {
                float2 g0 = cmulc(xs0[j + 20], xs0[j + 20 - dd]);
                float2 g1 = cmulc(xs1[j + 20], xs1[j + 20 - dd]);
                Gs[j] = make_float2(g0.x + g1.x, g0.y + g1.y);
            }
            __syncthreads();
            // S2 = sum_{n1i} w[n1i,d] * Gs[tid + 39 - n1i]
            float2 acc = make_float2(0.f, 0.f);
            #pragma unroll
            for (int n1i = 0; n1i < ND; ++n1i) {
                float2 g = Gs[tid + 39 - n1i];
                float wxr = wrs[n1i][di], wxi = wis[n1i][di];
                acc.x += wxr * g.x - wxi * g.y;
                acc.y += wxr * g.y + wxi * g.x;
            }
            // deltaf contribution: S2 * xf[b,n,l-dd] = S2 * xs[n][tid+39-dd]
            int xvi = tid + 39 - dd;
            float2 c0 = cmul(acc, xs0[xvi]);
            float2 c1 = cmul(acc, xs1[xvi]);
            a0.x += c0.x; a0.y += c0.y;
            a1.x += c1.x; a1.y += c1.y;
            __syncthreads();   // before Gs overwrite for next di
        }
        int base = (b * 2) * (L_FFT * 2) + (l0 + tid) * 2;
        unsafeAtomicAdd(&df[base + 0], a0.x);
        unsafeAtomicAdd(&df[base + 1], a0.y);
        unsafeAtomicAdd(&df[base + L_FFT * 2 + 0], a1.x);
        unsafeAtomicAdd(&df[base + L_FFT * 2 + 1], a1.y);
        __syncthreads();   // drain each wave's atomics
        if (tid == 0) {
            __threadfence();   // push any L2-resident atomic results to coherence point
            __hip_atomic_fetch_add(&cnt[32], 1, __ATOMIC_RELAXED, __HIP_MEMORY_SCOPE_AGENT);
        }
    }
    if (blk >= NB * NM) return;

    // wait for all 80 blocks' df contributions
    if (tid == 0)
        while (__hip_atomic_load(&cnt[32], __ATOMIC_RELAXED, __HIP_MEMORY_SCOPE_AGENT) < NBLK)
            __builtin_amdgcn_s_sleep(1);
    __syncthreads();

    // ---------------- P3: inverse FFT + epilogue, blocks 0-3 ---------------------
    {
        int b = blk >> 1, n = blk & 1;
        const float2* dfv = (const float2*)df + blk * L_FFT;
        #pragma unroll
        for (int it = 0; it < 4; ++it) {
            int t = tid + it * NT;
            bufA[t] = agent_load(&dfv[t]);               // sc1: read from MALL
        }
        build_tw<1>(tw, tid);
        float2* res = fft2048_r4<1>(bufA, bufB, tw, tid);
        float P = 1e-3f * __powf(10.f, task[b * 4] * 0.1f) * 0.5f;   // /N with N=2
        float scale = P * (1.0f / (float)L_FFT);                     // fold ifft 1/L
        for (int t = CROP + tid; t < L_FFT - CROP; t += NT) {
            int gi = (b * L_FFT + t) * NM + n;
            float2 dv = res[t];
            int oi = ((b * LOUT + (t - CROP)) * NM + n) * 2;
            out[oi]     = xr[gi] + dv.x * scale;
            out[oi + 1] = xi[gi] + dv.y * scale;
        }
    }
}

extern "C" void kernel_launch(void* const* d_in, const int* in_sizes, int n_in,
                              void* d_out, int out_size, void* d_ws, size_t ws_size,
                              hipStream_t stream) {
    const float* xr   = (const float*)d_in[0];
    const float* xi   = (const float*)d_in[1];
    const float* task = (const float*)d_in[2];
    const float* wr   = (const float*)d_in[3];
    const float* wi   = (const float*)d_in[4];
    // d_in[5], d_in[6]: fc_br / fc_bi -- bias lands only at t=0 after IFFT, cropped out.
    float* out = (float*)d_out;

    float2* ws = (float2*)d_ws;
    float2* xf  = ws;                        // 8192 float2  [b*2+n][l], sc1-accessed
    float*  df  = (float*)(ws + 8192);       // 16384 float  [b*2+n][l][2], atomic-accumulated
    int*    cnt = (int*)(df + 16384);        // cnt[0]=ready, cnt[32]=done

    // Zero df + flags every call (ws poisoned once, never re-poisoned between replays).
    hipMemsetAsync((void*)df, 0, 16384 * sizeof(float) + 256, stream);

    hipLaunchKernelGGL(fused_kernel, dim3(NBLK), dim3(NT), 0, stream,
                       xr, xi, task, wr, wi, out, xf, df, cnt);
}